// Round 1
// 386.481 us; speedup vs baseline: 1.0138x; 1.0138x over previous
//
#include <hip/hip_runtime.h>
#include <math.h>

static constexpr int BATCH = 4;
static constexpr int SEQ   = 2048;
static constexpr int DIM   = 1024;

typedef __attribute__((ext_vector_type(8))) short     bf16x8;  // MFMA A/B frag (4 VGPRs)
typedef __attribute__((ext_vector_type(4))) float     f32x4;   // MFMA C/D frag

// fp32 -> bf16 (RNE) and back, bit-exact helpers for hi/lo splitting
__device__ __forceinline__ unsigned short f2b(float v) {
    unsigned int u = __float_as_uint(v);
    u = u + 0x7fffu + ((u >> 16) & 1u);
    return (unsigned short)(u >> 16);
}
__device__ __forceinline__ float b2f(unsigned short h) {
    return __uint_as_float(((unsigned int)h) << 16);
}

// ---------------------------------------------------------------------------
// convert_x: fp32 -> (hi, lo) bf16, elementwise.
// ---------------------------------------------------------------------------
__global__ __launch_bounds__(256) void convert_x_kernel(
    const float* __restrict__ X, unsigned short* __restrict__ hi,
    unsigned short* __restrict__ lo)
{
    const int i = blockIdx.x * 256 + threadIdx.x;   // float4 index
    const float4 v = ((const float4*)X)[i];
    ushort4 h, l;
    h.x = f2b(v.x); l.x = f2b(v.x - b2f(h.x));
    h.y = f2b(v.y); l.y = f2b(v.y - b2f(h.y));
    h.z = f2b(v.z); l.z = f2b(v.z - b2f(h.z));
    h.w = f2b(v.w); l.w = f2b(v.w - b2f(h.w));
    ((ushort4*)hi)[i] = h;
    ((ushort4*)lo)[i] = l;
}

// ---------------------------------------------------------------------------
// convert_wqk: Wq (y=0) / Wk (y=1) fp32 -> hi/lo bf16, NO transpose.
// ---------------------------------------------------------------------------
__global__ __launch_bounds__(256) void convert_wqk_kernel(
    const float* __restrict__ Wq, const float* __restrict__ Wk,
    unsigned short* __restrict__ hi, unsigned short* __restrict__ lo)
{
    const int z = blockIdx.y;
    const float* __restrict__ W = z ? Wk : Wq;
    const int i = blockIdx.x * 256 + threadIdx.x;   // float4 index within matrix
    const int o = z * (DIM * DIM / 4) + i;
    const float4 v = ((const float4*)W)[i];
    ushort4 h, l;
    h.x = f2b(v.x); l.x = f2b(v.x - b2f(h.x));
    h.y = f2b(v.y); l.y = f2b(v.y - b2f(h.y));
    h.z = f2b(v.z); l.z = f2b(v.z - b2f(h.z));
    h.w = f2b(v.w); l.w = f2b(v.w - b2f(h.w));
    ((ushort4*)hi)[o] = h;
    ((ushort4*)lo)[o] = l;
}

// ---------------------------------------------------------------------------
// convert_wv: Wv[k][n] fp32 -> WvT[n][k] hi bf16 (V is single-term).
// ---------------------------------------------------------------------------
__global__ __launch_bounds__(256) void convert_wv_kernel(
    const float* __restrict__ W, unsigned short* __restrict__ WT)
{
    __shared__ float t[32][33];
    const int n0 = blockIdx.x * 32, k0 = blockIdx.y * 32;
    const int tx = threadIdx.x & 31, ty = threadIdx.x >> 5;  // ty: 0..7
#pragma unroll
    for (int i = 0; i < 4; ++i)
        t[ty + i * 8][tx] = W[(size_t)(k0 + ty + i * 8) * DIM + (n0 + tx)];
    __syncthreads();
#pragma unroll
    for (int i = 0; i < 4; ++i)
        WT[(size_t)(n0 + ty + i * 8) * DIM + (k0 + tx)] = f2b(t[tx][ty + i * 8]);
}

// ---------------------------------------------------------------------------
// Async staging of a (rows x 32)-elem bf16 tile via global_load_lds w=16.
// XOR-swizzled unpadded 64 B rows; wave-uniform LDS dest. Works for any
// block size that is a multiple of 64 (each wave stages 32 rows).
// ---------------------------------------------------------------------------
__device__ __forceinline__ void stage_async(
    const unsigned short* __restrict__ g, int gstride, int row0, int k0,
    unsigned short* lds, int tid)
{
    const int w = tid >> 6, lane = tid & 63;
    const int c = (lane & 3) ^ ((lane >> 4) & 3);   // global chunk this lane fetches
#pragma unroll
    for (int h = 0; h < 2; ++h) {
        const int row = 32 * w + 16 * h + (lane >> 2);
        const unsigned short* src = g + (size_t)(row0 + row) * gstride + k0 + 8 * c;
        unsigned short* dst = lds + (32 * w + 16 * h) * 32;   // wave-uniform
        __builtin_amdgcn_global_load_lds(
            (const __attribute__((address_space(1))) void*)src,
            (__attribute__((address_space(3))) void*)dst, 16, 0, 0);
    }
}

__device__ __forceinline__ bf16x8 fragr(const unsigned short* lds, int row, int qsw)
{
    return *(const bf16x8*)(lds + row * 32 + qsw * 8);
}

// ---------------------------------------------------------------------------
// m_gemm: Mt = Wk . Wq^T  (so Mt[j][i] = sum_o Wq[i][o] Wk[j][o]), 3-term
// split bf16, 128x128 tile, K-split over z (4 chunks of 256). fp32 partials.
// ---------------------------------------------------------------------------
__global__ __launch_bounds__(256) void m_gemm_kernel(
    const unsigned short* __restrict__ Whi, const unsigned short* __restrict__ Wlo,
    float* __restrict__ Mtp)
{
    __shared__ unsigned short Ah[128 * 32], Al[128 * 32];
    __shared__ unsigned short Bh[128 * 32], Bl[128 * 32];

    const int tid = threadIdx.x;
    const int w = tid >> 6, lane = tid & 63;
    const int wm = (w >> 1) * 64, wn = (w & 1) * 64;
    const int m0 = blockIdx.y * 128, n0 = blockIdx.x * 128;
    const int z = blockIdx.z;                        // K chunk

    const unsigned short* __restrict__ Ahg = Whi + (size_t)DIM * DIM;  // Wk hi
    const unsigned short* __restrict__ Alg = Wlo + (size_t)DIM * DIM;  // Wk lo
    const unsigned short* __restrict__ Bhg = Whi;                      // Wq hi
    const unsigned short* __restrict__ Blg = Wlo;                      // Wq lo
    float* __restrict__ Cp = Mtp + (size_t)z * DIM * DIM;

    f32x4 acc[4][4];
#pragma unroll
    for (int i = 0; i < 4; ++i)
#pragma unroll
        for (int j = 0; j < 4; ++j) acc[i][j] = (f32x4){0.f, 0.f, 0.f, 0.f};

    const int fr = lane & 15, quad = lane >> 4;
    const int qsw = quad ^ ((fr >> 2) & 3);

    for (int k0 = z * 256; k0 < z * 256 + 256; k0 += 32) {
        stage_async(Ahg, DIM, m0, k0, Ah, tid);
        stage_async(Alg, DIM, m0, k0, Al, tid);
        stage_async(Bhg, DIM, n0, k0, Bh, tid);
        stage_async(Blg, DIM, n0, k0, Bl, tid);
        __syncthreads();

        bf16x8 ah[4], al[4];
#pragma unroll
        for (int mt = 0; mt < 4; ++mt) {
            ah[mt] = fragr(Ah, wm + mt * 16 + fr, qsw);
            al[mt] = fragr(Al, wm + mt * 16 + fr, qsw);
        }
#pragma unroll
        for (int nt = 0; nt < 4; ++nt) {
            const bf16x8 bh = fragr(Bh, wn + nt * 16 + fr, qsw);
            const bf16x8 bl = fragr(Bl, wn + nt * 16 + fr, qsw);
#pragma unroll
            for (int mt = 0; mt < 4; ++mt) {
                acc[mt][nt] = __builtin_amdgcn_mfma_f32_16x16x32_bf16(ah[mt], bh, acc[mt][nt], 0, 0, 0);
                acc[mt][nt] = __builtin_amdgcn_mfma_f32_16x16x32_bf16(ah[mt], bl, acc[mt][nt], 0, 0, 0);
                acc[mt][nt] = __builtin_amdgcn_mfma_f32_16x16x32_bf16(al[mt], bh, acc[mt][nt], 0, 0, 0);
            }
        }
        __syncthreads();
    }

    const int col = lane & 15, rq = lane >> 4;
#pragma unroll
    for (int mt = 0; mt < 4; ++mt)
#pragma unroll
        for (int nt = 0; nt < 4; ++nt)
#pragma unroll
            for (int e = 0; e < 4; ++e) {
                const int m = m0 + wm + mt * 16 + rq * 4 + e;
                const int n = n0 + wn + nt * 16 + col;
                Cp[(size_t)m * DIM + n] = acc[mt][nt][e];
            }
}

// ---------------------------------------------------------------------------
// m_reduce: sum 4 K-split partials, split to hi/lo bf16.
// ---------------------------------------------------------------------------
__global__ __launch_bounds__(256) void m_reduce_kernel(
    const float* __restrict__ Mtp, unsigned short* __restrict__ Mthi,
    unsigned short* __restrict__ Mtlo)
{
    const int i = blockIdx.x * 256 + threadIdx.x;   // float4 index
    const size_t q = (size_t)DIM * DIM / 4;
    const float4 a = ((const float4*)Mtp)[i];
    const float4 b = ((const float4*)Mtp)[i + q];
    const float4 c = ((const float4*)Mtp)[i + 2 * q];
    const float4 d = ((const float4*)Mtp)[i + 3 * q];
    const float4 v = make_float4(a.x + b.x + c.x + d.x, a.y + b.y + c.y + d.y,
                                 a.z + b.z + c.z + d.z, a.w + b.w + c.w + d.w);
    ushort4 h, l;
    h.x = f2b(v.x); l.x = f2b(v.x - b2f(h.x));
    h.y = f2b(v.y); l.y = f2b(v.y - b2f(h.y));
    h.z = f2b(v.z); l.z = f2b(v.z - b2f(h.z));
    h.w = f2b(v.w); l.w = f2b(v.w - b2f(h.w));
    ((ushort4*)Mthi)[i] = h;
    ((ushort4*)Mtlo)[i] = l;
}

// ---------------------------------------------------------------------------
// yv_gemm: z=0 -> Y = X @ Mt^T (3-term, hi/lo out, [8192][1024])
//          z=1 -> V = X @ WvT^T (1-term), written TRANSPOSED as Vt[b][d][s]
// ---------------------------------------------------------------------------
__global__ __launch_bounds__(256) void yv_gemm_kernel(
    const unsigned short* __restrict__ Xhi, const unsigned short* __restrict__ Xlo,
    const unsigned short* __restrict__ Mthi, const unsigned short* __restrict__ Mtlo,
    const unsigned short* __restrict__ WvT,
    unsigned short* __restrict__ Yhi, unsigned short* __restrict__ Ylo,
    unsigned short* __restrict__ Vt)
{
    __shared__ unsigned short Ah[128 * 32], Al[128 * 32];
    __shared__ unsigned short Bh[128 * 32], Bl[128 * 32];

    const int tid = threadIdx.x;
    const int w = tid >> 6, lane = tid & 63;
    const int wm = (w >> 1) * 64, wn = (w & 1) * 64;
    const int m0 = blockIdx.y * 128, n0 = blockIdx.x * 128;
    const int z = blockIdx.z;
    const bool full = (z == 0);

    const unsigned short* __restrict__ Bhg = full ? Mthi : WvT;
    const unsigned short* __restrict__ Blg = Mtlo;

    f32x4 acc[4][4];
#pragma unroll
    for (int i = 0; i < 4; ++i)
#pragma unroll
        for (int j = 0; j < 4; ++j) acc[i][j] = (f32x4){0.f, 0.f, 0.f, 0.f};

    const int fr = lane & 15, quad = lane >> 4;
    const int qsw = quad ^ ((fr >> 2) & 3);

    for (int k0 = 0; k0 < DIM; k0 += 32) {
        stage_async(Xhi, DIM, m0, k0, Ah, tid);
        stage_async(Bhg, DIM, n0, k0, Bh, tid);
        if (full) {
            stage_async(Xlo, DIM, m0, k0, Al, tid);
            stage_async(Blg, DIM, n0, k0, Bl, tid);
        }
        __syncthreads();

        bf16x8 ah[4], al[4];
#pragma unroll
        for (int mt = 0; mt < 4; ++mt)
            ah[mt] = fragr(Ah, wm + mt * 16 + fr, qsw);
        if (full) {
#pragma unroll
            for (int mt = 0; mt < 4; ++mt)
                al[mt] = fragr(Al, wm + mt * 16 + fr, qsw);
        }
#pragma unroll
        for (int nt = 0; nt < 4; ++nt) {
            const bf16x8 bh = fragr(Bh, wn + nt * 16 + fr, qsw);
#pragma unroll
            for (int mt = 0; mt < 4; ++mt)
                acc[mt][nt] = __builtin_amdgcn_mfma_f32_16x16x32_bf16(ah[mt], bh, acc[mt][nt], 0, 0, 0);
            if (full) {
                const bf16x8 bl = fragr(Bl, wn + nt * 16 + fr, qsw);
#pragma unroll
                for (int mt = 0; mt < 4; ++mt) {
                    acc[mt][nt] = __builtin_amdgcn_mfma_f32_16x16x32_bf16(ah[mt], bl, acc[mt][nt], 0, 0, 0);
                    acc[mt][nt] = __builtin_amdgcn_mfma_f32_16x16x32_bf16(al[mt], bh, acc[mt][nt], 0, 0, 0);
                }
            }
        }
        __syncthreads();
    }

    const int col = lane & 15, rq = lane >> 4;
    if (full) {
#pragma unroll
        for (int mt = 0; mt < 4; ++mt)
#pragma unroll
            for (int nt = 0; nt < 4; ++nt)
#pragma unroll
                for (int e = 0; e < 4; ++e) {
                    const int m = m0 + wm + mt * 16 + rq * 4 + e;
                    const int n = n0 + wn + nt * 16 + col;
                    const float v = acc[mt][nt][e];
                    const unsigned short h = f2b(v);
                    Yhi[(size_t)m * DIM + n] = h;
                    Ylo[(size_t)m * DIM + n] = f2b(v - b2f(h));
                }
    } else {
        // V: write transposed, Vt[b][n][s], 4 consecutive s per ushort4
#pragma unroll
        for (int mt = 0; mt < 4; ++mt)
#pragma unroll
            for (int nt = 0; nt < 4; ++nt) {
                const int m = m0 + wm + mt * 16 + rq * 4;      // 4-aligned
                const int bb = m >> 11, s = m & (SEQ - 1);
                const int n = n0 + wn + nt * 16 + col;
                ushort4 pk;
                pk.x = f2b(acc[mt][nt][0]);
                pk.y = f2b(acc[mt][nt][1]);
                pk.z = f2b(acc[mt][nt][2]);
                pk.w = f2b(acc[mt][nt][3]);
                *(ushort4*)(Vt + (size_t)bb * DIM * SEQ + (size_t)n * SEQ + s) = pk;
            }
    }
}

// ---------------------------------------------------------------------------
// s_gemm256: S[b] = (Y[b] . X[b]^T) * 1/32, masked to -inf. fp32 output.
// 256x256 tile, BK=32, 512 threads (8 waves, 2Mx4N, 128x64 per wave).
// Phase-split schedule (T3/T4/T5): double-buffered LDS (128 KiB dynamic),
// prefetch issued a full K-step ahead, raw s_barrier between the 4 MFMA
// phases (loads stay in flight across barriers), single vmcnt(0) drain per
// K-step, s_setprio(1) around each MFMA cluster. Math order per acc element
// (hh, hl, lh; fp32 accum) identical to the 128^2 version.
// ---------------------------------------------------------------------------
__global__ __launch_bounds__(512, 2) void s_gemm256_kernel(
    const unsigned short* __restrict__ Yhi, const unsigned short* __restrict__ Ylo,
    const unsigned short* __restrict__ Xhi, const unsigned short* __restrict__ Xlo,
    const int* __restrict__ mask, float* __restrict__ Sc)
{
    extern __shared__ unsigned short smem[];
    // layout (ushort offsets): buffer c at c*32768:
    //   Ah = +0, Al = +8192, Bh = +16384, Bl = +24576   (each 256x32)

    const int tid = threadIdx.x;
    const int w = tid >> 6, lane = tid & 63;
    const int wm = (w >> 2) * 128, wn = (w & 3) * 64;
    const int m0 = blockIdx.y * 256, n0 = blockIdx.x * 256;
    const int b = blockIdx.z;

    const unsigned short* __restrict__ Ahg = Yhi + (size_t)b * SEQ * DIM;
    const unsigned short* __restrict__ Alg = Ylo + (size_t)b * SEQ * DIM;
    const unsigned short* __restrict__ Bhg = Xhi + (size_t)b * SEQ * DIM;
    const unsigned short* __restrict__ Blg = Xlo + (size_t)b * SEQ * DIM;
    float* __restrict__ Sb = Sc + (size_t)b * SEQ * SEQ;

    f32x4 acc[8][4];
#pragma unroll
    for (int i = 0; i < 8; ++i)
#pragma unroll
        for (int j = 0; j < 4; ++j) acc[i][j] = (f32x4){0.f, 0.f, 0.f, 0.f};

    const int fr = lane & 15, quad = lane >> 4;
    const int qsw = quad ^ ((fr >> 2) & 3);

    // prologue: stage K-step 0 into buffer 0, drain, sync
    stage_async(Ahg, DIM, m0, 0, smem + 0,     tid);
    stage_async(Alg, DIM, m0, 0, smem + 8192,  tid);
    stage_async(Bhg, DIM, n0, 0, smem + 16384, tid);
    stage_async(Blg, DIM, n0, 0, smem + 24576, tid);
    asm volatile("s_waitcnt vmcnt(0)" ::: "memory");
    __builtin_amdgcn_s_barrier();

    for (int it = 0; it < DIM / 32; ++it) {
        const int cur = (it & 1) * 32768;
        const int nxt = cur ^ 32768;
        const unsigned short* Ah = smem + cur;
        const unsigned short* Al = smem + cur + 8192;
        const unsigned short* Bh = smem + cur + 16384;
        const unsigned short* Bl = smem + cur + 24576;
        const int k1 = it * 32 + 32;
        const bool pf = (it < DIM / 32 - 1);

        bf16x8 ah[4], al[4], bh[2], bl[2];

        // ---- phase 0: quadrant (mhalf=0, npair=0) ----
        if (pf) {
            stage_async(Ahg, DIM, m0, k1, smem + nxt,        tid);
            stage_async(Alg, DIM, m0, k1, smem + nxt + 8192, tid);
        }
#pragma unroll
        for (int mt = 0; mt < 4; ++mt) {
            ah[mt] = fragr(Ah, wm + mt * 16 + fr, qsw);
            al[mt] = fragr(Al, wm + mt * 16 + fr, qsw);
        }
#pragma unroll
        for (int j = 0; j < 2; ++j) {
            bh[j] = fragr(Bh, wn + j * 16 + fr, qsw);
            bl[j] = fragr(Bl, wn + j * 16 + fr, qsw);
        }
        __builtin_amdgcn_s_barrier();
        __builtin_amdgcn_s_setprio(1);
#pragma unroll
        for (int j = 0; j < 2; ++j)
#pragma unroll
            for (int mt = 0; mt < 4; ++mt) {
                acc[mt][j] = __builtin_amdgcn_mfma_f32_16x16x32_bf16(ah[mt], bh[j], acc[mt][j], 0, 0, 0);
                acc[mt][j] = __builtin_amdgcn_mfma_f32_16x16x32_bf16(ah[mt], bl[j], acc[mt][j], 0, 0, 0);
                acc[mt][j] = __builtin_amdgcn_mfma_f32_16x16x32_bf16(al[mt], bh[j], acc[mt][j], 0, 0, 0);
            }
        __builtin_amdgcn_s_setprio(0);

        // ---- phase 1: quadrant (mhalf=0, npair=1) ----
        if (pf) {
            stage_async(Bhg, DIM, n0, k1, smem + nxt + 16384, tid);
            stage_async(Blg, DIM, n0, k1, smem + nxt + 24576, tid);
        }
#pragma unroll
        for (int j = 0; j < 2; ++j) {
            bh[j] = fragr(Bh, wn + 32 + j * 16 + fr, qsw);
            bl[j] = fragr(Bl, wn + 32 + j * 16 + fr, qsw);
        }
        __builtin_amdgcn_s_barrier();
        __builtin_amdgcn_s_setprio(1);
#pragma unroll
        for (int j = 0; j < 2; ++j)
#pragma unroll
            for (int mt = 0; mt < 4; ++mt) {
                acc[mt][2 + j] = __builtin_amdgcn_mfma_f32_16x16x32_bf16(ah[mt], bh[j], acc[mt][2 + j], 0, 0, 0);
                acc[mt][2 + j] = __builtin_amdgcn_mfma_f32_16x16x32_bf16(ah[mt], bl[j], acc[mt][2 + j], 0, 0, 0);
                acc[mt][2 + j] = __builtin_amdgcn_mfma_f32_16x16x32_bf16(al[mt], bh[j], acc[mt][2 + j], 0, 0, 0);
            }
        __builtin_amdgcn_s_setprio(0);

        // ---- phase 2: quadrant (mhalf=1, npair=1) ---- (b frags reused)
#pragma unroll
        for (int mt = 0; mt < 4; ++mt) {
            ah[mt] = fragr(Ah, wm + 64 + mt * 16 + fr, qsw);
            al[mt] = fragr(Al, wm + 64 + mt * 16 + fr, qsw);
        }
        __builtin_amdgcn_s_barrier();
        __builtin_amdgcn_s_setprio(1);
#pragma unroll
        for (int j = 0; j < 2; ++j)
#pragma unroll
            for (int mt = 0; mt < 4; ++mt) {
                acc[4 + mt][2 + j] = __builtin_amdgcn_mfma_f32_16x16x32_bf16(ah[mt], bh[j], acc[4 + mt][2 + j], 0, 0, 0);
                acc[4 + mt][2 + j] = __builtin_amdgcn_mfma_f32_16x16x32_bf16(ah[mt], bl[j], acc[4 + mt][2 + j], 0, 0, 0);
                acc[4 + mt][2 + j] = __builtin_amdgcn_mfma_f32_16x16x32_bf16(al[mt], bh[j], acc[4 + mt][2 + j], 0, 0, 0);
            }
        __builtin_amdgcn_s_setprio(0);

        // ---- phase 3: quadrant (mhalf=1, npair=0) ---- (a frags reused)
#pragma unroll
        for (int j = 0; j < 2; ++j) {
            bh[j] = fragr(Bh, wn + j * 16 + fr, qsw);
            bl[j] = fragr(Bl, wn + j * 16 + fr, qsw);
        }
        __builtin_amdgcn_s_barrier();
        __builtin_amdgcn_s_setprio(1);
#pragma unroll
        for (int j = 0; j < 2; ++j)
#pragma unroll
            for (int mt = 0; mt < 4; ++mt) {
                acc[4 + mt][j] = __builtin_amdgcn_mfma_f32_16x16x32_bf16(ah[mt], bh[j], acc[4 + mt][j], 0, 0, 0);
                acc[4 + mt][j] = __builtin_amdgcn_mfma_f32_16x16x32_bf16(ah[mt], bl[j], acc[4 + mt][j], 0, 0, 0);
                acc[4 + mt][j] = __builtin_amdgcn_mfma_f32_16x16x32_bf16(al[mt], bh[j], acc[4 + mt][j], 0, 0, 0);
            }
        __builtin_amdgcn_s_setprio(0);

        // K-step boundary: own prefetch loads must be in LDS before any wave
        // reads buf[nxt] next iteration (issued 1-4 phases ago -> cheap drain)
        asm volatile("s_waitcnt vmcnt(0)" ::: "memory");
        __builtin_amdgcn_s_barrier();
    }

    const int col = lane & 15, rq = lane >> 4;
#pragma unroll
    for (int mt = 0; mt < 8; ++mt)
#pragma unroll
        for (int nt = 0; nt < 4; ++nt)
#pragma unroll
            for (int e = 0; e < 4; ++e) {
                const int m = m0 + wm + mt * 16 + rq * 4 + e;
                const int n = n0 + wn + nt * 16 + col;
                const float v = acc[mt][nt][e] * 0.03125f;
                Sb[(size_t)m * SEQ + n] = mask[(size_t)m * SEQ + n] ? -INFINITY : v;
            }
}

// ---------------------------------------------------------------------------
// Row softmax on pre-masked, pre-scaled fp32 S; writes bf16 P in place
// (row r -> first 2048 ushorts of the row's 16 KB).
// ---------------------------------------------------------------------------
__global__ __launch_bounds__(256) void softmax_kernel(float* __restrict__ Sc)
{
    const int r = blockIdx.x;          // b*2048 + m
    float* __restrict__ row = Sc + (size_t)r * SEQ;

    const int tid  = threadIdx.x;
    const int lane = tid & 63;
    const int wid  = tid >> 6;

    float x[8];
    float mx = -INFINITY;
#pragma unroll
    for (int j = 0; j < 8; ++j) {
        x[j] = row[tid + j * 256];
        mx = fmaxf(mx, x[j]);
    }
    __shared__ float redm[4];
#pragma unroll
    for (int off = 32; off > 0; off >>= 1)
        mx = fmaxf(mx, __shfl_down(mx, off, 64));
    if (lane == 0) redm[wid] = mx;
    __syncthreads();
    mx = fmaxf(fmaxf(redm[0], redm[1]), fmaxf(redm[2], redm[3]));

    float sum = 0.f;
#pragma unroll
    for (int j = 0; j < 8; ++j) {
        const float e = __expf(x[j] - mx);
        x[j] = e;
        sum += e;
    }
    __shared__ float reds[4];
#pragma unroll
    for (int off = 32; off > 0; off >>= 1)
        sum += __shfl_down(sum, off, 64);
    if (lane == 0) reds[wid] = sum;
    __syncthreads();
    sum = (reds[0] + reds[1]) + (reds[2] + reds[3]);

    const float inv = 1.0f / sum;
    unsigned short* __restrict__ prow = (unsigned short*)row;
#pragma unroll
    for (int j = 0; j < 8; ++j)
        prow[tid + j * 256] = f2b(x[j] * inv);
}

// ---------------------------------------------------------------------------
// O[b] = P[b] @ V[b]: single bf16 MFMA, BK=64 (two staged sub-tiles/barrier).
// A = P rows (stride 4096 ushorts), B = Vt rows (n-major, k contiguous).
// ---------------------------------------------------------------------------
__global__ __launch_bounds__(256) void pv_mfma_kernel(
    const unsigned short* __restrict__ P, const unsigned short* __restrict__ Vt,
    float* __restrict__ O)
{
    __shared__ unsigned short As[2][128 * 32], Bs[2][128 * 32];

    const int tid = threadIdx.x;
    const int w = tid >> 6, lane = tid & 63;
    const int wm = (w >> 1) * 64, wn = (w & 1) * 64;
    const int m0 = blockIdx.y * 128, n0 = blockIdx.x * 128;
    const int b = blockIdx.z;

    const unsigned short* __restrict__ Ag = P + (size_t)b * SEQ * (2 * SEQ);
    const unsigned short* __restrict__ Bg = Vt + (size_t)b * DIM * SEQ;
    float* __restrict__ Ob = O + (size_t)b * SEQ * DIM;

    f32x4 acc[4][4];
#pragma unroll
    for (int i = 0; i < 4; ++i)
#pragma unroll
        for (int j = 0; j < 4; ++j) acc[i][j] = (f32x4){0.f, 0.f, 0.f, 0.f};

    const int fr = lane & 15, quad = lane >> 4;
    const int qsw = quad ^ ((fr >> 2) & 3);

    for (int k0 = 0; k0 < SEQ; k0 += 64) {
        stage_async(Ag, 2 * SEQ, m0, k0,      As[0], tid);
        stage_async(Ag, 2 * SEQ, m0, k0 + 32, As[1], tid);
        stage_async(Bg, SEQ,     n0, k0,      Bs[0], tid);
        stage_async(Bg, SEQ,     n0, k0 + 32, Bs[1], tid);
        __syncthreads();

#pragma unroll
        for (int s = 0; s < 2; ++s) {
            bf16x8 af[4];
#pragma unroll
            for (int mt = 0; mt < 4; ++mt)
                af[mt] = fragr(As[s], wm + mt * 16 + fr, qsw);
#pragma unroll
            for (int nt = 0; nt < 4; ++nt) {
                const bf16x8 bfg = fragr(Bs[s], wn + nt * 16 + fr, qsw);
#pragma unroll
                for (int mt = 0; mt < 4; ++mt)
                    acc[mt][nt] = __builtin_amdgcn_mfma_f32_16x16x32_bf16(af[mt], bfg, acc[mt][nt], 0, 0, 0);
            }
        }
        __syncthreads();
    }

    const int col = lane & 15, rq = lane >> 4;
#pragma unroll
    for (int mt = 0; mt < 4; ++mt)
#pragma unroll
        for (int nt = 0; nt < 4; ++nt)
#pragma unroll
            for (int e = 0; e < 4; ++e) {
                const int m = m0 + wm + mt * 16 + rq * 4 + e;
                const int n = n0 + wn + nt * 16 + col;
                Ob[(size_t)m * DIM + n] = acc[mt][nt][e];
            }
}

// ---------------------------------------------------------------------------
// Workspace layout (bytes), ws = 167 772 160:
//   Xhi/Xlo/Yhi/Ylo/Vt : 5 x 16 777 216   (bf16 [8192][1024]-sized each)
//   Mthi/Mtlo          : 2 x  2 097 152   (bf16 [1024][1024])
//   Sc                 : 67 108 864       (fp32 [4][2048][2048])  -> 155.2 MB
// Transients aliased INSIDE Sc (consumed before s_gemm writes Sc):
//   Whi/Wlo (2x4.2 MB) + WvT (2.1 MB) + Mtp (4x4.2 MB fp32) = 27.3 MB
// P (bf16) written in place into Sc rows (row r at ushort offset r*4096).
// ---------------------------------------------------------------------------
extern "C" void kernel_launch(void* const* d_in, const int* in_sizes, int n_in,
                              void* d_out, int out_size, void* d_ws, size_t ws_size,
                              hipStream_t stream)
{
    const float* x    = (const float*)d_in[0];
    const int*   mask = (const int*)d_in[1];
    const float* wq   = (const float*)d_in[2];
    const float* wk   = (const float*)d_in[3];
    const float* wv   = (const float*)d_in[4];
    float* out = (float*)d_out;

    const size_t NQ = (size_t)BATCH * SEQ * DIM;     // 8 388 608
    const size_t NM = (size_t)DIM * DIM;             // 1 048 576
    unsigned short* Xhi  = (unsigned short*)d_ws;
    unsigned short* Xlo  = Xhi + NQ;
    unsigned short* Yhi  = Xlo + NQ;
    unsigned short* Ylo  = Yhi + NQ;
    unsigned short* Vt   = Ylo + NQ;
    unsigned short* Mthi = Vt + NQ;
    unsigned short* Mtlo = Mthi + NM;
    float* Sc = (float*)(Mtlo + NM);

    unsigned short* Whi = (unsigned short*)Sc;       // transient aliases
    unsigned short* Wlo = Whi + 2 * NM;
    unsigned short* WvT = Wlo + 2 * NM;
    float* Mtp = (float*)(WvT + NM);

    // one-time: allow 128 KiB dynamic LDS for the 256^2 S-gemm
    static bool lds_attr_set = false;
    if (!lds_attr_set) {
        (void)hipFuncSetAttribute((const void*)s_gemm256_kernel,
                                  hipFuncAttributeMaxDynamicSharedMemorySize,
                                  131072);
        lds_attr_set = true;
    }

    // 1. X -> hi/lo bf16
    convert_x_kernel<<<dim3(NQ / 4 / 256), 256, 0, stream>>>(x, Xhi, Xlo);
    // 2. Wq/Wk -> hi/lo bf16 (no transpose); Wv -> WvT hi bf16
    convert_wqk_kernel<<<dim3(NM / 4 / 256, 2), 256, 0, stream>>>(wq, wk, Whi, Wlo);
    convert_wv_kernel<<<dim3(32, 32), 256, 0, stream>>>(wv, WvT);
    // 3. Mt = Wk.Wq^T (K-split x4, fp32 partials), then reduce + hi/lo split
    m_gemm_kernel<<<dim3(8, 8, 4), 256, 0, stream>>>(Whi, Wlo, Mtp);
    m_reduce_kernel<<<dim3(NM / 4 / 256), 256, 0, stream>>>(Mtp, Mthi, Mtlo);
    // 4. z=0: Y = X.Mt^T (hi/lo out); z=1: V = X.WvT^T written as Vt[b][d][s]
    yv_gemm_kernel<<<dim3(DIM / 128, (BATCH * SEQ) / 128, 2), 256, 0, stream>>>(
        Xhi, Xlo, Mthi, Mtlo, WvT, Yhi, Ylo, Vt);
    // 5. S = masked, scaled Y.X^T per batch (fp32 scores), 256^2 phase-split
    s_gemm256_kernel<<<dim3(SEQ / 256, SEQ / 256, BATCH), 512, 131072, stream>>>(
        Yhi, Ylo, Xhi, Xlo, mask, Sc);
    // 6. softmax; writes bf16 P in place
    softmax_kernel<<<dim3(BATCH * SEQ), 256, 0, stream>>>(Sc);
    // 7. O = P @ V
    pv_mfma_kernel<<<dim3(DIM / 128, SEQ / 128, BATCH), 256, 0, stream>>>(
        (const unsigned short*)Sc, Vt, out);
}